// Round 1
// baseline (21.822 us; speedup 1.0000x reference)
//
#include <hip/hip_runtime.h>

// Grid2Points: out[p, c] = p < points_num ? max(x[idx[p], c], 0) : 0
// x: [F=450000, C=64] f32, idx: [N=200000] i32, out: [N, C] f32.
// One 16-lane group per point; each lane moves one float4 (16B) of the
// 256B row -> fully coalesced gather reads and writes.

__global__ void gather_relu_kernel(const int* __restrict__ idx,
                                   const float* __restrict__ x,
                                   const int* __restrict__ points_num_p,
                                   float* __restrict__ out,
                                   int n_points) {
    const int C4 = 16;  // 64 channels / 4 per float4
    int t = blockIdx.x * blockDim.x + threadIdx.x;
    int p = t >> 4;           // point index
    int v = t & 15;           // float4 slot within the row
    if (p >= n_points) return;

    const int pn = *points_num_p;

    float4 r;
    if (p < pn) {
        int row = idx[p];
        const float4* src = reinterpret_cast<const float4*>(x) + (size_t)row * C4 + v;
        r = *src;
        r.x = fmaxf(r.x, 0.0f);
        r.y = fmaxf(r.y, 0.0f);
        r.z = fmaxf(r.z, 0.0f);
        r.w = fmaxf(r.w, 0.0f);
    } else {
        r = make_float4(0.0f, 0.0f, 0.0f, 0.0f);
    }

    float4* dst = reinterpret_cast<float4*>(out) + (size_t)p * C4 + v;
    *dst = r;
}

extern "C" void kernel_launch(void* const* d_in, const int* in_sizes, int n_in,
                              void* d_out, int out_size, void* d_ws, size_t ws_size,
                              hipStream_t stream) {
    const int*   idx = (const int*)d_in[0];    // rv_coors [1,1,1,N]
    const float* x   = (const float*)d_in[1];  // rv_x_i   [1,F,64]
    const int*   pn  = (const int*)d_in[2];    // points_num (scalar on device)
    float*       out = (float*)d_out;

    int n_points = in_sizes[0];                // N = 200000
    int total = n_points * 16;                 // 16 float4 lanes per point
    int block = 256;
    int grid = (total + block - 1) / block;

    gather_relu_kernel<<<grid, block, 0, stream>>>(idx, x, pn, out, n_points);
}

// Round 2
// 21.758 us; speedup vs baseline: 1.0029x; 1.0029x over previous
//
#include <hip/hip_runtime.h>

// Grid2Points: out[p, c] = p < points_num ? max(x[idx[p], c], 0) : 0
// x: [F=450000, C=64] f32, idx: [N=200000] i32, out: [N, C] f32.
// 16 lanes per point, one float4 per lane (256B row fully coalesced).
// 2 points per thread for load ILP. Non-temporal stores keep L2/L3
// reserved for the reused grid rows (x fits in the 256MB L3).

typedef float v4f __attribute__((ext_vector_type(4)));

__global__ __launch_bounds__(256)
void gather_relu_kernel(const int* __restrict__ idx,
                        const float* __restrict__ x,
                        const int* __restrict__ points_num_p,
                        float* __restrict__ out,
                        int n_points) {
    const int C4 = 16;  // 64 channels / 4 floats per vec
    int t = blockIdx.x * blockDim.x + threadIdx.x;
    int v = t & 15;            // float4 slot within the row
    int pg = t >> 4;           // point-pair index
    int p0 = pg * 2;
    if (p0 >= n_points) return;

    const int pn = *points_num_p;
    const v4f* xv = reinterpret_cast<const v4f*>(x);
    v4f* ov = reinterpret_cast<v4f*>(out);

    // issue both gathers before using either (ILP)
    int p1 = p0 + 1;
    bool ok0 = (p0 < pn);
    bool ok1 = (p1 < n_points) && (p1 < pn);

    v4f r0 = {0.f, 0.f, 0.f, 0.f};
    v4f r1 = {0.f, 0.f, 0.f, 0.f};

    if (ok0) {
        int row0 = __builtin_nontemporal_load(idx + p0);
        r0 = xv[(size_t)row0 * C4 + v];
    }
    if (ok1) {
        int row1 = __builtin_nontemporal_load(idx + p1);
        r1 = xv[(size_t)row1 * C4 + v];
    }

    r0.x = fmaxf(r0.x, 0.f); r0.y = fmaxf(r0.y, 0.f);
    r0.z = fmaxf(r0.z, 0.f); r0.w = fmaxf(r0.w, 0.f);
    r1.x = fmaxf(r1.x, 0.f); r1.y = fmaxf(r1.y, 0.f);
    r1.z = fmaxf(r1.z, 0.f); r1.w = fmaxf(r1.w, 0.f);

    __builtin_nontemporal_store(r0, ov + (size_t)p0 * C4 + v);
    if (p1 < n_points)
        __builtin_nontemporal_store(r1, ov + (size_t)p1 * C4 + v);
}

extern "C" void kernel_launch(void* const* d_in, const int* in_sizes, int n_in,
                              void* d_out, int out_size, void* d_ws, size_t ws_size,
                              hipStream_t stream) {
    const int*   idx = (const int*)d_in[0];    // rv_coors [1,1,1,N]
    const float* x   = (const float*)d_in[1];  // rv_x_i   [1,F,64]
    const int*   pn  = (const int*)d_in[2];    // points_num (scalar on device)
    float*       out = (float*)d_out;

    int n_points = in_sizes[0];                // N = 200000
    int pairs = (n_points + 1) / 2;
    int total = pairs * 16;                    // 16 lanes per point-pair
    int block = 256;
    int grid = (total + block - 1) / block;

    gather_relu_kernel<<<grid, block, 0, stream>>>(idx, x, pn, out, n_points);
}

// Round 3
// 21.371 us; speedup vs baseline: 1.0211x; 1.0181x over previous
//
#include <hip/hip_runtime.h>

// Grid2Points: out[p, c] = p < points_num ? max(x[idx[p], c], 0) : 0
// x: [F=450000, C=64] f32, idx: [N=200000] i32, out: [N, C] f32.
// 16 lanes per point (one float4/lane, 256B row coalesced).
// 4 points per thread, strided by G (= total 16-lane groups) so that:
//   - all 4 idx loads issue before any gather (MLP depth ~5)
//   - all 4 gathers are in flight together
//   - each store instruction is a contiguous 1KB per wave.

typedef float v4f __attribute__((ext_vector_type(4)));

__global__ __launch_bounds__(256)
void gather_relu_kernel(const int* __restrict__ idx,
                        const float* __restrict__ x,
                        const int* __restrict__ points_num_p,
                        float* __restrict__ out,
                        int n_points, int G) {
    const int C4 = 16;  // 64 channels / 4 floats per vec
    int t = blockIdx.x * blockDim.x + threadIdx.x;
    int v = t & 15;            // float4 slot within the row
    int g = t >> 4;            // group id = base point
    if (g >= G) return;

    const int pn = *points_num_p;
    const v4f* xv = reinterpret_cast<const v4f*>(x);
    v4f* ov = reinterpret_cast<v4f*>(out);

    int p[4];
    int rows[4];
    bool ok[4];
    #pragma unroll
    for (int k = 0; k < 4; ++k) {
        p[k] = g + k * G;
        ok[k] = (p[k] < n_points) && (p[k] < pn);
        rows[k] = ok[k] ? idx[p[k]] : 0;       // 4 idx loads up front
    }

    v4f r[4];
    #pragma unroll
    for (int k = 0; k < 4; ++k) {
        v4f z = {0.f, 0.f, 0.f, 0.f};
        r[k] = ok[k] ? xv[(size_t)rows[k] * C4 + v] : z;  // 4 gathers in flight
    }

    #pragma unroll
    for (int k = 0; k < 4; ++k) {
        r[k].x = fmaxf(r[k].x, 0.f);
        r[k].y = fmaxf(r[k].y, 0.f);
        r[k].z = fmaxf(r[k].z, 0.f);
        r[k].w = fmaxf(r[k].w, 0.f);
        if (p[k] < n_points)
            __builtin_nontemporal_store(r[k], ov + (size_t)p[k] * C4 + v);
    }
}

extern "C" void kernel_launch(void* const* d_in, const int* in_sizes, int n_in,
                              void* d_out, int out_size, void* d_ws, size_t ws_size,
                              hipStream_t stream) {
    const int*   idx = (const int*)d_in[0];    // rv_coors [1,1,1,N]
    const float* x   = (const float*)d_in[1];  // rv_x_i   [1,F,64]
    const int*   pn  = (const int*)d_in[2];    // points_num (scalar on device)
    float*       out = (float*)d_out;

    int n_points = in_sizes[0];                // N = 200000
    int G = (n_points + 3) / 4;                // 16-lane groups (points per batch)
    int total = G * 16;
    int block = 256;
    int grid = (total + block - 1) / block;

    gather_relu_kernel<<<grid, block, 0, stream>>>(idx, x, pn, out, n_points, G);
}